// Round 1
// baseline (1034.655 us; speedup 1.0000x reference)
//
#include <hip/hip_runtime.h>

namespace {

constexpr int CIN = 32, CO = 32, H = 128, W = 128, SY = 32, B = 4;
constexpr int TH = 8, TW = 16;          // output tile per block
constexpr int HH = TH + 2, HW = TW + 2; // haloed tile: 10 x 18
constexpr int TILES_X = W / TW;         // 8
constexpr int TILES_Y = H / TH;         // 16
constexpr int TILES = TILES_X * TILES_Y;// 128 tiles per image
constexpr int IMG = H * W;              // 16384
constexpr int NT = B * CO * H * W;      // new_target elements = 2097152
constexpr int WSTRIDE = 2 * CIN * 9;    // 576 floats per co in W

// conv over one staged image tile: acc[x] += sum_{ci,ky,kx} w * in
__device__ __forceinline__ void conv_tile(float acc[TW],
                                          const float* __restrict__ in_lds,
                                          const float* __restrict__ w_lds,
                                          int sub, int co)
{
  #pragma unroll 4
  for (int ci = 0; ci < CIN; ++ci) {
    #pragma unroll
    for (int ky = 0; ky < 3; ++ky) {
      const float* rp = &in_lds[ci * (HH * HW) + (sub + ky) * HW];
      float row[HW];
      #pragma unroll
      for (int i = 0; i < HW; ++i) row[i] = rp[i];
      #pragma unroll
      for (int kx = 0; kx < 3; ++kx) {
        const float w = w_lds[(ci * 9 + ky * 3 + kx) * 32 + co];
        #pragma unroll
        for (int x = 0; x < TW; ++x) acc[x] = fmaf(w, row[x + kx], acc[x]);
      }
    }
  }
}

__device__ __forceinline__ void stage_tile(float* __restrict__ in_lds,
                                           const float* __restrict__ src,
                                           int py0, int px0, int tid)
{
  for (int e = tid; e < CIN * HH * HW; e += 256) {
    const int ci = e / (HH * HW);
    const int r  = e - ci * (HH * HW);
    const int iy = r / HW, ix = r - iy * HW;
    const int y = py0 - 1 + iy, x = px0 - 1 + ix;
    float v = 0.f;
    if ((unsigned)y < (unsigned)H && (unsigned)x < (unsigned)W)
      v = src[ci * IMG + y * W + x];
    in_lds[e] = v;
  }
}

__global__ __launch_bounds__(256, 2)
void cross_kernel(const float* __restrict__ target,
                  const float* __restrict__ support,
                  const float* __restrict__ Wfull,
                  const float* __restrict__ bias,
                  float* __restrict__ out)
{
  __shared__ float w_lds[288 * 32];          // 36864 B, layout [ci*9+ky*3+kx][co]
  __shared__ float in_lds[CIN * HH * HW];    // 23040 B

  const int tid = threadIdx.x;
  const int co  = tid >> 3;   // 0..31
  const int sub = tid & 7;    // output row within tile, 0..7

  const int b  = blockIdx.x / TILES;
  const int t  = blockIdx.x % TILES;
  const int ty = t / TILES_X, tx = t % TILES_X;
  const int py0 = ty * TH, px0 = tx * TW;

  // ---- stage Wx (ci 0..31), layout transposed to [k-index][co] ----
  for (int e = tid; e < 288 * 32; e += 256) {
    const int c = e & 31, idx = e >> 5;
    const int ci = idx / 9, r = idx - ci * 9;
    w_lds[e] = Wfull[c * WSTRIDE + ci * 9 + r];
  }
  // ---- stage target tile ----
  stage_tile(in_lds, target + b * (CIN * IMG), py0, px0, tid);
  __syncthreads();

  // cx + bias, kept in registers for the whole sy loop
  float accx[TW];
  #pragma unroll
  for (int i = 0; i < TW; ++i) accx[i] = 0.f;
  conv_tile(accx, in_lds, w_lds, sub, co);
  const float bv = bias[co];
  #pragma unroll
  for (int i = 0; i < TW; ++i) accx[i] += bv;

  __syncthreads();  // all reads of Wx / target tile done

  // ---- stage Wy (ci 32..63) ----
  for (int e = tid; e < 288 * 32; e += 256) {
    const int c = e & 31, idx = e >> 5;
    const int ci = idx / 9, r = idx - ci * 9;
    w_lds[e] = Wfull[c * WSTRIDE + (ci + 32) * 9 + r];
  }

  float sum[TW];
  #pragma unroll
  for (int i = 0; i < TW; ++i) sum[i] = 0.f;

  for (int sy = 0; sy < SY; ++sy) {
    stage_tile(in_lds, support + (b * SY + sy) * (CIN * IMG), py0, px0, tid);
    __syncthreads();   // tile (and, at sy=0, Wy) visible

    float acc[TW];
    #pragma unroll
    for (int i = 0; i < TW; ++i) acc[i] = 0.f;
    conv_tile(acc, in_lds, w_lds, sub, co);

    // interaction[b, sy, co, py0+sub, px0 .. px0+15]
    float* op = out + NT + ((((size_t)b * SY + sy) * CO + co) * H + (py0 + sub)) * W + px0;
    float4* o4 = reinterpret_cast<float4*>(op);
    #pragma unroll
    for (int q = 0; q < TW / 4; ++q) {
      o4[q] = make_float4(accx[4*q+0] + acc[4*q+0],
                          accx[4*q+1] + acc[4*q+1],
                          accx[4*q+2] + acc[4*q+2],
                          accx[4*q+3] + acc[4*q+3]);
    }
    #pragma unroll
    for (int i = 0; i < TW; ++i) sum[i] += acc[i];

    __syncthreads();   // before next overwrite of in_lds
  }

  // new_target[b, 0, co, py0+sub, px0..] = cx + bias + mean_sy(cy)
  float* npt = out + (((size_t)b * CO + co) * H + (py0 + sub)) * W + px0;
  float4* n4 = reinterpret_cast<float4*>(npt);
  constexpr float inv = 1.0f / SY;
  #pragma unroll
  for (int q = 0; q < TW / 4; ++q) {
    n4[q] = make_float4(accx[4*q+0] + sum[4*q+0] * inv,
                        accx[4*q+1] + sum[4*q+1] * inv,
                        accx[4*q+2] + sum[4*q+2] * inv,
                        accx[4*q+3] + sum[4*q+3] * inv);
  }
}

} // namespace

extern "C" void kernel_launch(void* const* d_in, const int* in_sizes, int n_in,
                              void* d_out, int out_size, void* d_ws, size_t ws_size,
                              hipStream_t stream)
{
  (void)in_sizes; (void)n_in; (void)out_size; (void)d_ws; (void)ws_size;
  const float* target  = (const float*)d_in[0];
  const float* support = (const float*)d_in[1];
  const float* Wfull   = (const float*)d_in[2];
  const float* bias    = (const float*)d_in[3];
  float* out = (float*)d_out;
  cross_kernel<<<dim3(B * TILES), 256, 0, stream>>>(target, support, Wfull, bias, out);
}

// Round 2
// 346.891 us; speedup vs baseline: 2.9826x; 2.9826x over previous
//
#include <hip/hip_runtime.h>

typedef short bf16x8 __attribute__((ext_vector_type(8)));
typedef float f32x4  __attribute__((ext_vector_type(4)));

namespace {

constexpr int CIN = 32, CO = 32, Himg = 128, Wimg = 128, SY = 32, Bb = 4;
constexpr int IMG = Himg * Wimg;                 // 16384
constexpr int NT  = Bb * CO * IMG;               // new_target elems (2097152)
constexpr int TROWS = 6, TCOLS = 66;             // halo'd 4-row x 64-col tile
constexpr int NPIX  = TROWS * TCOLS;             // 396
constexpr int LDSB  = 16 * NPIX * 4;             // 25344 bytes

__device__ __forceinline__ unsigned short f2bf(float f) {
  unsigned u = __builtin_bit_cast(unsigned, f);
  return (unsigned short)((u + 0x7FFFu + ((u >> 16) & 1u)) >> 16);   // RNE
}

// stage one image tile: rows y0-1..y0+4, cols x0-1..x0+64, all 32 ci,
// into LDS layout [pixel][ci] bf16 with XOR swizzle (byte ^= (pix&7)<<4)
__device__ __forceinline__ void stage(char* __restrict__ lds,
                                      const float* __restrict__ src,
                                      int y0, int x0, int tid)
{
  for (int e = tid; e < 16 * NPIX; e += 256) {
    const int ch  = e / NPIX;            // ci pair 0..15 -> ci = 2*ch
    const int pix = e - ch * NPIX;       // iy*66 + ix
    const int iy  = pix / TCOLS;
    const int ix  = pix - iy * TCOLS;
    const int y = y0 - 1 + iy, x = x0 - 1 + ix;
    float v0 = 0.f, v1 = 0.f;
    if ((unsigned)y < (unsigned)Himg && (unsigned)x < (unsigned)Wimg) {
      const float* p = src + (size_t)(2 * ch) * IMG + y * Wimg + x;
      v0 = p[0];
      v1 = p[IMG];
    }
    const unsigned pk = (unsigned)f2bf(v0) | ((unsigned)f2bf(v1) << 16);
    const int ba = (pix * 64 + ch * 4) ^ ((pix & 7) << 4);
    *reinterpret_cast<unsigned*>(lds + ba) = pk;
  }
}

// per-lane A fragments (weights) for 9 taps x 2 co-tiles; ci = kc*8+j
__device__ __forceinline__ void load_w(bf16x8 wf[9][2],
                                       const float* __restrict__ Wfull,
                                       int cioff, int lane)
{
  const int lx = lane & 15, kc = lane >> 4;
  #pragma unroll
  for (int tap = 0; tap < 9; ++tap) {
    #pragma unroll
    for (int m = 0; m < 2; ++m) {
      const float* base = Wfull + (size_t)((m * 16 + lx) * 64 + cioff + kc * 8) * 9 + tap;
      bf16x8 w;
      #pragma unroll
      for (int j = 0; j < 8; ++j) w[j] = (short)f2bf(base[j * 9]);
      wf[tap][m] = w;
    }
  }
}

// 9-tap conv over the staged tile: acc[m][n] (co-tile m, 16-px tile n)
__device__ __forceinline__ void conv(f32x4 acc[2][4],
                                     const char* __restrict__ lds,
                                     const bf16x8 wf[9][2],
                                     int wrow, int lane)
{
  const int lx = lane & 15, kc = lane >> 4;
  #pragma unroll
  for (int ky = 0; ky < 3; ++ky) {
    #pragma unroll
    for (int kx = 0; kx < 3; ++kx) {
      const int tap = ky * 3 + kx;
      #pragma unroll
      for (int n = 0; n < 4; ++n) {
        const int p  = (wrow + ky) * TCOLS + n * 16 + lx + kx;
        const int ba = (p * 64 + kc * 16) ^ ((p & 7) << 4);
        const bf16x8 bfrag = *reinterpret_cast<const bf16x8*>(lds + ba);
        acc[0][n] = __builtin_amdgcn_mfma_f32_16x16x32_bf16(wf[tap][0], bfrag, acc[0][n], 0, 0, 0);
        acc[1][n] = __builtin_amdgcn_mfma_f32_16x16x32_bf16(wf[tap][1], bfrag, acc[1][n], 0, 0, 0);
      }
    }
  }
}

__global__ __launch_bounds__(256, 2)
void cross_mfma(const float* __restrict__ target,
                const float* __restrict__ support,
                const float* __restrict__ Wfull,
                const float* __restrict__ bias,
                float* __restrict__ out)
{
  __shared__ char lds[LDSB];

  const int tid  = threadIdx.x;
  const int lane = tid & 63;
  const int wrow = tid >> 6;            // wave id = row within 4-row band
  const int lx = lane & 15, kc = lane >> 4;

  const int bid = blockIdx.x;
  const int syh = bid & 1;              // sy half (0: sy 0-15, 1: sy 16-31)
  const int xh  = (bid >> 1) & 1;       // x half
  const int yb  = (bid >> 2) & 31;      // y band (4 rows)
  const int b   = bid >> 7;             // batch
  const int y0 = yb * 4, x0 = xh * 64;
  const int y  = y0 + wrow;

  bf16x8 wf[9][2];

  // ---- phase 1: cx = conv(target, Wx), reused across all sy ----
  load_w(wf, Wfull, 0, lane);
  stage(lds, target + (size_t)b * CIN * IMG, y0, x0, tid);
  __syncthreads();

  f32x4 cx[2][4];
  #pragma unroll
  for (int m = 0; m < 2; ++m)
    #pragma unroll
    for (int n = 0; n < 4; ++n)
      cx[m][n] = f32x4{0.f, 0.f, 0.f, 0.f};
  conv(cx, lds, wf, wrow, lane);

  #pragma unroll
  for (int m = 0; m < 2; ++m)
    #pragma unroll
    for (int j = 0; j < 4; ++j) {
      const float bv = bias[m * 16 + kc * 4 + j];
      #pragma unroll
      for (int n = 0; n < 4; ++n) cx[m][n][j] += bv;
    }

  load_w(wf, Wfull, 32, lane);          // switch registers to Wy
  __syncthreads();                      // target-tile reads complete

  // ---- phase 2: loop over this block's 16 sy images ----
  f32x4 sum[2][4];
  #pragma unroll
  for (int m = 0; m < 2; ++m)
    #pragma unroll
    for (int n = 0; n < 4; ++n)
      sum[m][n] = f32x4{0.f, 0.f, 0.f, 0.f};

  for (int i = 0; i < 16; ++i) {
    const int sy = syh * 16 + i;
    stage(lds, support + (size_t)(b * SY + sy) * CIN * IMG, y0, x0, tid);
    __syncthreads();

    f32x4 acc[2][4];
    #pragma unroll
    for (int m = 0; m < 2; ++m)
      #pragma unroll
      for (int n = 0; n < 4; ++n)
        acc[m][n] = cx[m][n];           // start from cx+bias, add cy via MFMA
    conv(acc, lds, wf, wrow, lane);

    #pragma unroll
    for (int m = 0; m < 2; ++m)
      #pragma unroll
      for (int n = 0; n < 4; ++n) {
        sum[m][n] += acc[m][n];
        const size_t basei = (size_t)NT +
            (((size_t)(b * SY + sy) * CO + m * 16 + kc * 4) * Himg + y) * Wimg +
            x0 + n * 16 + lx;
        #pragma unroll
        for (int j = 0; j < 4; ++j)
          out[basei + (size_t)j * IMG] = acc[m][n][j];
      }
    __syncthreads();                    // before next tile overwrites LDS
  }

  // ---- phase 3: new_target = cx + bias + mean_sy(cy) via 2-way atomic ----
  // sum = 16*(cx+bias) + sum(cy over our 16 sy)
  #pragma unroll
  for (int m = 0; m < 2; ++m)
    #pragma unroll
    for (int n = 0; n < 4; ++n) {
      const size_t baseo =
          ((size_t)(b * CO + m * 16 + kc * 4) * Himg + y) * Wimg + x0 + n * 16 + lx;
      #pragma unroll
      for (int j = 0; j < 4; ++j) {
        const float cyPart = (sum[m][n][j] - 16.f * cx[m][n][j]) * (1.f / 32.f);
        const float v = cyPart + (syh == 0 ? cx[m][n][j] : 0.f);
        atomicAdd(&out[baseo + (size_t)j * IMG], v);
      }
    }
}

} // namespace

extern "C" void kernel_launch(void* const* d_in, const int* in_sizes, int n_in,
                              void* d_out, int out_size, void* d_ws, size_t ws_size,
                              hipStream_t stream)
{
  (void)in_sizes; (void)n_in; (void)out_size; (void)d_ws; (void)ws_size;
  const float* target  = (const float*)d_in[0];
  const float* support = (const float*)d_in[1];
  const float* Wfull   = (const float*)d_in[2];
  const float* bias    = (const float*)d_in[3];
  float* out = (float*)d_out;

  hipMemsetAsync(d_out, 0, (size_t)NT * sizeof(float), stream);
  cross_mfma<<<dim3(512), 256, 0, stream>>>(target, support, Wfull, bias, out);
}